// Round 1
// baseline (27.678 us; speedup 1.0000x reference)
//
#include <hip/hip_runtime.h>

#define BATCH      16384
#define NF         1024
#define TREE_DEPTH 10

// One wave (64 lanes) per batch row.
// Lane l owns columns {4*l + 256*k + j : k in 0..3, j in 0..3}.
// W rows 0..9 per-lane slices live in registers (loaded once per wave).
// Leaf slice (16 consecutive leaves per lane) lives in registers.
__global__ __launch_bounds__(256, 2)
void sdt_kernel(const float* __restrict__ x,
                const float* __restrict__ W,
                const float* __restrict__ b,
                const float* __restrict__ leaf,
                float* __restrict__ out,
                int nwaves_total)
{
    const int lane = threadIdx.x & 63;
    const int wid  = (int)((blockIdx.x * blockDim.x + threadIdx.x) >> 6);

    // ---- preload W slices: Wr[d][k] = W[d][256k + 4l .. +3] ----
    float4 Wr[10][4];
#pragma unroll
    for (int d = 0; d < 10; ++d)
#pragma unroll
        for (int k = 0; k < 4; ++k)
            Wr[d][k] = *reinterpret_cast<const float4*>(W + d * NF + k * 256 + 4 * lane);

    float bias[10];
#pragma unroll
    for (int d = 0; d < 10; ++d) bias[d] = b[d];

    // ---- preload leaf slice: Lv[i] = leaf[16*lane + i] ----
    float Lv[16];
#pragma unroll
    for (int k = 0; k < 4; ++k) {
        float4 t = *reinterpret_cast<const float4*>(leaf + 16 * lane + 4 * k);
        Lv[4 * k + 0] = t.x; Lv[4 * k + 1] = t.y;
        Lv[4 * k + 2] = t.z; Lv[4 * k + 3] = t.w;
    }

    for (int row = wid; row < BATCH; row += nwaves_total) {
        // ---- coalesced x loads: lane l reads float4 at 256k + 4l ----
        const float* xr = x + (size_t)row * NF;
        float4 xv[4];
#pragma unroll
        for (int k = 0; k < 4; ++k)
            xv[k] = *reinterpret_cast<const float4*>(xr + k * 256 + 4 * lane);

        // ---- 10 partial dots ----
        float acc[10];
#pragma unroll
        for (int d = 0; d < 10; ++d) {
            float a = 0.0f;
#pragma unroll
            for (int k = 0; k < 4; ++k) {
                a = fmaf(xv[k].x, Wr[d][k].x, a);
                a = fmaf(xv[k].y, Wr[d][k].y, a);
                a = fmaf(xv[k].z, Wr[d][k].z, a);
                a = fmaf(xv[k].w, Wr[d][k].w, a);
            }
            acc[d] = a;
        }

        // ---- wave-reduce each of the 10 dots (butterfly, 6 steps) ----
#pragma unroll
        for (int d = 0; d < 10; ++d) {
            float a = acc[d];
#pragma unroll
            for (int off = 32; off > 0; off >>= 1)
                a += __shfl_xor(a, off, 64);
            acc[d] = a;
        }

        // ---- gates ----
        float g[10];
#pragma unroll
        for (int d = 0; d < 10; ++d) {
            float z = acc[d] + bias[d];
            g[d] = 1.0f / (1.0f + __expf(-z));
        }

        // ---- DP over leaves: contract LSB-first.
        // bit_d(leaf) = (leaf >> (9-d)) & 1; level 9 contracts leaf LSB with g[9].
        float s9[8];
#pragma unroll
        for (int j = 0; j < 8; ++j)
            s9[j] = fmaf(g[9], Lv[2 * j + 1] - Lv[2 * j], Lv[2 * j]);
        float s8[4];
#pragma unroll
        for (int j = 0; j < 4; ++j)
            s8[j] = fmaf(g[8], s9[2 * j + 1] - s9[2 * j], s9[2 * j]);
        float s7[2];
#pragma unroll
        for (int j = 0; j < 2; ++j)
            s7[j] = fmaf(g[7], s8[2 * j + 1] - s8[2 * j], s8[2 * j]);
        float s6 = fmaf(g[6], s7[1] - s7[0], s7[0]);

        // ---- per-lane 6-bit path weight: lane index = bits d=0..5, d=0 is MSB ----
        float w = 1.0f;
#pragma unroll
        for (int d = 0; d < 6; ++d) {
            int bit = (lane >> (5 - d)) & 1;
            float f = bit ? g[d] : (1.0f - g[d]);
            w *= f;
        }

        // ---- weighted wave-sum ----
        float v = w * s6;
#pragma unroll
        for (int off = 32; off > 0; off >>= 1)
            v += __shfl_xor(v, off, 64);

        if (lane == 0) out[row] = v;
    }
}

extern "C" void kernel_launch(void* const* d_in, const int* in_sizes, int n_in,
                              void* d_out, int out_size, void* d_ws, size_t ws_size,
                              hipStream_t stream) {
    const float* x    = (const float*)d_in[0];
    const float* W    = (const float*)d_in[1];
    const float* b    = (const float*)d_in[2];
    const float* leaf = (const float*)d_in[3];
    float* out = (float*)d_out;

    const int blocks  = 512;           // 2048 waves -> 8 rows per wave
    const int threads = 256;
    const int nwaves  = blocks * threads / 64;

    sdt_kernel<<<blocks, threads, 0, stream>>>(x, W, b, leaf, out, nwaves);
}

// Round 2
// 26.250 us; speedup vs baseline: 1.0544x; 1.0544x over previous
//
#include <hip/hip_runtime.h>

#define BATCH      16384
#define NF         1024
#define TREE_DEPTH 10

// One wave (64 lanes) per batch row, software-pipelined over rows.
// Lane l owns columns {4*l + 256*k + j : k in 0..3, j in 0..3}.
// W rows 0..9 per-lane slices live in registers (loaded once per wave).
// Leaf slice (16 consecutive leaves per lane) lives in registers.
// Next row's x is prefetched (double-buffered) while current row computes.
__global__ __launch_bounds__(256, 2)
void sdt_kernel(const float* __restrict__ x,
                const float* __restrict__ W,
                const float* __restrict__ b,
                const float* __restrict__ leaf,
                float* __restrict__ out,
                int nwaves_total)
{
    const int lane = threadIdx.x & 63;
    const int wid  = (int)((blockIdx.x * blockDim.x + threadIdx.x) >> 6);

    // ---- preload W slices: Wr[d][k] = W[d][256k + 4l .. +3] ----
    float4 Wr[10][4];
#pragma unroll
    for (int d = 0; d < 10; ++d)
#pragma unroll
        for (int k = 0; k < 4; ++k)
            Wr[d][k] = *reinterpret_cast<const float4*>(W + d * NF + k * 256 + 4 * lane);

    // bias: uniform loads -> compiler scalarizes to SGPRs
    float bias[10];
#pragma unroll
    for (int d = 0; d < 10; ++d) bias[d] = b[d];

    // ---- preload leaf slice: Lv[i] = leaf[16*lane + i] ----
    float Lv[16];
#pragma unroll
    for (int k = 0; k < 4; ++k) {
        float4 t = *reinterpret_cast<const float4*>(leaf + 16 * lane + 4 * k);
        Lv[4 * k + 0] = t.x; Lv[4 * k + 1] = t.y;
        Lv[4 * k + 2] = t.z; Lv[4 * k + 3] = t.w;
    }

    // ---- prologue: load first row ----
    float4 xv[4];
    {
        const float* xr = x + (size_t)wid * NF;
#pragma unroll
        for (int k = 0; k < 4; ++k)
            xv[k] = *reinterpret_cast<const float4*>(xr + k * 256 + 4 * lane);
    }

    for (int row = wid; row < BATCH; row += nwaves_total) {
        // ---- prefetch next row (issued before compute; waited at copy below) ----
        float4 xn[4];
        const int nrow = row + nwaves_total;
        if (nrow < BATCH) {
            const float* xr = x + (size_t)nrow * NF;
#pragma unroll
            for (int k = 0; k < 4; ++k)
                xn[k] = *reinterpret_cast<const float4*>(xr + k * 256 + 4 * lane);
        }

        // ---- 10 partial dots ----
        float acc[10];
#pragma unroll
        for (int d = 0; d < 10; ++d) {
            float a = 0.0f;
#pragma unroll
            for (int k = 0; k < 4; ++k) {
                a = fmaf(xv[k].x, Wr[d][k].x, a);
                a = fmaf(xv[k].y, Wr[d][k].y, a);
                a = fmaf(xv[k].z, Wr[d][k].z, a);
                a = fmaf(xv[k].w, Wr[d][k].w, a);
            }
            acc[d] = a;
        }

        // ---- wave-reduce each of the 10 dots (butterfly, 6 steps) ----
#pragma unroll
        for (int d = 0; d < 10; ++d) {
            float a = acc[d];
#pragma unroll
            for (int off = 32; off > 0; off >>= 1)
                a += __shfl_xor(a, off, 64);
            acc[d] = a;
        }

        // ---- gates (fast rcp: ~1 ulp, output scale ~0.01, threshold 2.4e-5) ----
        float g[10];
#pragma unroll
        for (int d = 0; d < 10; ++d) {
            float z = acc[d] + bias[d];
            g[d] = __builtin_amdgcn_rcpf(1.0f + __expf(-z));
        }

        // ---- DP over leaves: contract leaf LSB (depth 9) upward ----
        float s9[8];
#pragma unroll
        for (int j = 0; j < 8; ++j)
            s9[j] = fmaf(g[9], Lv[2 * j + 1] - Lv[2 * j], Lv[2 * j]);
        float s8[4];
#pragma unroll
        for (int j = 0; j < 4; ++j)
            s8[j] = fmaf(g[8], s9[2 * j + 1] - s9[2 * j], s9[2 * j]);
        float s7[2];
#pragma unroll
        for (int j = 0; j < 2; ++j)
            s7[j] = fmaf(g[7], s8[2 * j + 1] - s8[2 * j], s8[2 * j]);
        float s6 = fmaf(g[6], s7[1] - s7[0], s7[0]);

        // ---- per-lane 6-bit path weight: lane index = bits d=0..5, d=0 MSB ----
        float w = 1.0f;
#pragma unroll
        for (int d = 0; d < 6; ++d) {
            int bit = (lane >> (5 - d)) & 1;
            w *= bit ? g[d] : (1.0f - g[d]);
        }

        // ---- weighted wave-sum ----
        float v = w * s6;
#pragma unroll
        for (int off = 32; off > 0; off >>= 1)
            v += __shfl_xor(v, off, 64);

        if (lane == 0) out[row] = v;

        // ---- rotate pipeline (vmcnt wait for xn lands here, after compute) ----
#pragma unroll
        for (int k = 0; k < 4; ++k) xv[k] = xn[k];
    }
}

extern "C" void kernel_launch(void* const* d_in, const int* in_sizes, int n_in,
                              void* d_out, int out_size, void* d_ws, size_t ws_size,
                              hipStream_t stream) {
    const float* x    = (const float*)d_in[0];
    const float* W    = (const float*)d_in[1];
    const float* b    = (const float*)d_in[2];
    const float* leaf = (const float*)d_in[3];
    float* out = (float*)d_out;

    const int blocks  = 512;           // 2048 waves = resident capacity at 2 waves/SIMD
    const int threads = 256;
    const int nwaves  = blocks * threads / 64;

    sdt_kernel<<<blocks, threads, 0, stream>>>(x, W, b, leaf, out, nwaves);
}